// Round 1
// baseline (465.338 us; speedup 1.0000x reference)
//
#include <hip/hip_runtime.h>
#include <math.h>

#define B_    128
#define T_    24
#define NN    300
#define EE    9000
#define GG    (B_ * T_)
#define GRUH  12
#define OUTF  1200

// ---------------------------------------------------------------------------
// Kernel 1: per-graph EdgeGAT + mean pool, collapsed to scalar S[g].
// Single edge-parallel pass with LDS float atomics (no max-subtraction:
// logits are bounded ~|10|, exp() is fp32-safe, and the num/den ratio is
// mathematically identical to the max-shifted softmax).
//   den[n] = sum_{e: dst==n} exp(v_e)
//   num[n] = sum_{e: dst==n} exp(v_e) * x[src_e]
//   S[g]   = sum_n num[n]/den[n]
// ---------------------------------------------------------------------------
__global__ __launch_bounds__(320) void gat_pool(
    const float* __restrict__ x, const float* __restrict__ ew,
    const int* __restrict__ src, const int* __restrict__ dst,
    const float* __restrict__ w_node, const float* __restrict__ w_edge,
    const float* __restrict__ attn_l, const float* __restrict__ attn_r,
    const float* __restrict__ attn_e,
    float* __restrict__ S)
{
    __shared__ float xs[NN];
    __shared__ float den[NN];
    __shared__ float num[NN];
    __shared__ float red[5];

    const int g = blockIdx.x;
    const int tid = threadIdx.x;

    // scalar attention constants (tiny, L1/L2-broadcast)
    float cL = 0.f, cR = 0.f, cE = 0.f;
#pragma unroll
    for (int o = 0; o < 4; o++) {
        float wn = w_node[o];
        cL += wn * attn_l[o];
        cR += wn * attn_r[o];
        cE += w_edge[o] * attn_e[o];
    }

    const float* xrow = x + (size_t)g * NN;
    const float* erow = ew + (size_t)g * EE;

    for (int i = tid; i < NN; i += 320) {
        xs[i]  = xrow[i];
        den[i] = 0.f;
        num[i] = 0.f;
    }
    __syncthreads();

    // single edge pass: coalesced float4/int4, LDS gathers + LDS fp atomics
    const float4* __restrict__ erow4 = (const float4*)erow;  // 36000 B row, 16B-aligned
    const int4*   __restrict__ src4  = (const int4*)src;
    const int4*   __restrict__ dst4  = (const int4*)dst;

#define PROC(sj, dj, ev)                                        \
    {                                                           \
        float xsv = xs[(sj)];                                   \
        float v = fmaf(cL, xsv, fmaf(cR, xs[(dj)], cE * (ev))); \
        v = (v >= 0.f) ? v : 0.2f * v;                          \
        float ex = __expf(v);                                   \
        unsafeAtomicAdd(&den[(dj)], ex);                        \
        unsafeAtomicAdd(&num[(dj)], ex * xsv);                  \
    }

    const int nq = EE / 4;  // 2250, exact
    for (int q = tid; q < nq; q += 320) {
        const float4 e4 = erow4[q];
        const int4   s4 = src4[q];
        const int4   d4 = dst4[q];
        PROC(s4.x, d4.x, e4.x);
        PROC(s4.y, d4.y, e4.y);
        PROC(s4.z, d4.z, e4.z);
        PROC(s4.w, d4.w, e4.w);
    }
#undef PROC
    __syncthreads();

    // node pass: num/den, then block reduce (5 waves)
    float acc = 0.f;
    if (tid < NN) {
        float d = den[tid];
        if (d > 0.f) acc = num[tid] / d;
    }
    for (int off = 32; off > 0; off >>= 1) acc += __shfl_down(acc, off);
    if ((tid & 63) == 0) red[tid >> 6] = acc;
    __syncthreads();
    if (tid == 0) S[g] = red[0] + red[1] + red[2] + red[3] + red[4];
}

// ---------------------------------------------------------------------------
// Kernel 2: GRU (24 steps, hidden 12) in wave 0 via shuffles (0 barriers in
// the time loop), then FC (12 -> 1200) across all 256 threads.
// pooled[b,t,o] = (S[g]/N) * w_node[o] + gat_bias[o]
// ---------------------------------------------------------------------------
__device__ __forceinline__ float sigmoidf_(float v) { return 1.0f / (1.0f + __expf(-v)); }

__global__ __launch_bounds__(256) void gru_fc(
    const float* __restrict__ S,
    const float* __restrict__ w_node, const float* __restrict__ gat_bias,
    const float* __restrict__ w_ih, const float* __restrict__ w_hh,
    const float* __restrict__ b_ih, const float* __restrict__ b_hh,
    const float* __restrict__ fc_w, const float* __restrict__ fc_b,
    float* __restrict__ out)
{
    __shared__ float hsh[GRUH];

    const int b = blockIdx.x;
    const int tid = threadIdx.x;

    if (tid < 64) {  // wave 0 runs the whole GRU, barrier-free
        float wn[4], gb[4];
#pragma unroll
        for (int i = 0; i < 4; i++) {
            wn[i] = w_node[i] * (1.0f / (float)NN);
            gb[i] = gat_bias[i];
        }
        float wih[4] = {0.f, 0.f, 0.f, 0.f};
        float whh[12];
#pragma unroll
        for (int j = 0; j < 12; j++) whh[j] = 0.f;
        float bih = 0.f, bhh = 0.f;
        if (tid < 36) {
#pragma unroll
            for (int i = 0; i < 4; i++)  wih[i] = w_ih[tid * 4 + i];
#pragma unroll
            for (int j = 0; j < 12; j++) whh[j] = w_hh[tid * 12 + j];
            bih = b_ih[tid];
            bhh = b_hh[tid];
        }
        // preload this batch's 24 pooled scalars across lanes 0..23
        float srow = (tid < T_) ? S[(size_t)b * T_ + tid] : 0.f;

        float hreg = 0.f;          // lanes 0..11 hold h
        const int l = tid % 12;    // safe shuffle index for every lane

        for (int t = 0; t < T_; t++) {
            float Sg = __shfl(srow, t);
            float gi = bih, gh = bhh;
#pragma unroll
            for (int i = 0; i < 4; i++) gi += (Sg * wn[i] + gb[i]) * wih[i];
#pragma unroll
            for (int j = 0; j < 12; j++) gh += __shfl(hreg, j) * whh[j];
            float a   = gi + gh;                 // lane m<36: gate-preact m
            float aiz = __shfl(a, 12 + l);       // z-gate preact for lane l
            float gin = __shfl(gi, 24 + l);      // n-gate input part
            float ghn = __shfl(gh, 24 + l);      // n-gate hidden part
            if (tid < 12) {
                float r = sigmoidf_(a);
                float z = sigmoidf_(aiz);
                float n = tanhf(gin + r * ghn);
                hreg = (1.f - z) * n + z * hreg;
            }
        }
        if (tid < GRUH) hsh[tid] = hreg;
    }
    __syncthreads();

    // FC epilogue: 1200 outputs per batch across 256 lanes (fc_w L1/L2-resident)
    for (int j = tid; j < OUTF; j += 256) {
        float o = fc_b[j];
#pragma unroll
        for (int k = 0; k < GRUH; k++) o += hsh[k] * fc_w[j * GRUH + k];
        out[(size_t)b * OUTF + j] = o;
    }
}

// ---------------------------------------------------------------------------
extern "C" void kernel_launch(void* const* d_in, const int* in_sizes, int n_in,
                              void* d_out, int out_size, void* d_ws, size_t ws_size,
                              hipStream_t stream)
{
    const float* x        = (const float*)d_in[0];
    const float* ew       = (const float*)d_in[1];
    const int*   src      = (const int*)d_in[2];
    const int*   dst      = (const int*)d_in[3];
    const float* w_node   = (const float*)d_in[4];
    const float* w_edge   = (const float*)d_in[5];
    const float* attn_l   = (const float*)d_in[6];
    const float* attn_r   = (const float*)d_in[7];
    const float* attn_e   = (const float*)d_in[8];
    const float* gat_bias = (const float*)d_in[9];
    const float* w_ih     = (const float*)d_in[10];
    const float* w_hh     = (const float*)d_in[11];
    const float* b_ih     = (const float*)d_in[12];
    const float* b_hh     = (const float*)d_in[13];
    const float* fc_w     = (const float*)d_in[14];
    const float* fc_b     = (const float*)d_in[15];
    float* out = (float*)d_out;

    float* S = (float*)d_ws;  // GG floats

    gat_pool<<<GG, 320, 0, stream>>>(x, ew, src, dst, w_node, w_edge,
                                     attn_l, attn_r, attn_e, S);
    gru_fc<<<B_, 256, 0, stream>>>(S, w_node, gat_bias, w_ih, w_hh,
                                   b_ih, b_hh, fc_w, fc_b, out);
}

// Round 2
// 448.190 us; speedup vs baseline: 1.0383x; 1.0383x over previous
//
#include <hip/hip_runtime.h>
#include <math.h>

#define B_    128
#define T_    24
#define NN    300
#define EE    9000
#define GG    (B_ * T_)
#define GRUH  12
#define OUTF  1200

// ---------------------------------------------------------------------------
// Kernel 1: build CSR of edges grouped by dst (topology shared by all 3072
// graphs). Entries are int2(src, eid) so the hot kernel does ONE 8B load per
// edge for indices. Runs once, single block.
// ---------------------------------------------------------------------------
__global__ __launch_bounds__(1024) void build_csr(
    const int* __restrict__ src, const int* __restrict__ dst,
    int* __restrict__ row_ptr, int2* __restrict__ edge2)
{
    __shared__ int cnt[512];
    __shared__ int bufA[512], bufB[512];
    __shared__ int offs[NN];
    const int tid = threadIdx.x;

    for (int i = tid; i < 512; i += 1024) cnt[i] = 0;
    __syncthreads();
    for (int e = tid; e < EE; e += 1024) atomicAdd(&cnt[dst[e]], 1);
    __syncthreads();

    // Hillis-Steele inclusive scan over 512 (padded) elements
    int* cur = bufA; int* nxt = bufB;
    if (tid < 512) cur[tid] = cnt[tid];
    __syncthreads();
    for (int d = 1; d < 512; d <<= 1) {
        if (tid < 512) nxt[tid] = cur[tid] + (tid >= d ? cur[tid - d] : 0);
        __syncthreads();
        int* t = cur; cur = nxt; nxt = t;
    }
    if (tid <= NN) row_ptr[tid] = (tid == 0) ? 0 : cur[tid - 1];
    if (tid < NN)  offs[tid]    = (tid == 0) ? 0 : cur[tid - 1];
    __syncthreads();

    for (int e = tid; e < EE; e += 1024) {
        int d = dst[e];
        int pos = atomicAdd(&offs[d], 1);
        edge2[pos] = make_int2(src[e], e);
    }
}

// ---------------------------------------------------------------------------
// Kernel 2: per-graph EdgeGAT + mean pool -> scalar S[g].
// One lane per dst node, walking its contiguous CSR segment with register
// accumulators. No atomics, no evals buffer, 1.3 KB LDS. exp() without
// max-shift (logits bounded ~|6|; validated in round 1, absmax 3e-5).
//   den_n = sum exp(v_e), num_n = sum exp(v_e)*x[src_e], S[g] = sum num/den
// ---------------------------------------------------------------------------
__global__ __launch_bounds__(320) void gat_pool(
    const float* __restrict__ x, const float* __restrict__ ew,
    const float* __restrict__ w_node, const float* __restrict__ w_edge,
    const float* __restrict__ attn_l, const float* __restrict__ attn_r,
    const float* __restrict__ attn_e,
    const int* __restrict__ row_ptr, const int2* __restrict__ edge2,
    float* __restrict__ S)
{
    __shared__ float xs[NN];
    __shared__ float red[5];

    const int g = blockIdx.x;
    const int tid = threadIdx.x;

    // scalar attention constants (tiny, L1/L2-broadcast)
    float cL = 0.f, cR = 0.f, cE = 0.f;
#pragma unroll
    for (int o = 0; o < 4; o++) {
        float wn = w_node[o];
        cL += wn * attn_l[o];
        cR += wn * attn_r[o];
        cE += w_edge[o] * attn_e[o];
    }

    const float* xrow = x + (size_t)g * NN;
    const float* erow = ew + (size_t)g * EE;

    for (int i = tid; i < NN; i += 320) xs[i] = xrow[i];
    __syncthreads();

    float acc = 0.f;
    if (tid < NN) {
        const int beg = row_ptr[tid];
        const int end = row_ptr[tid + 1];
        const float vb = cR * xs[tid];   // dst term, hoisted (dst == own node)
        float den = 0.f, num = 0.f;
        for (int i = beg; i < end; i++) {
            const int2 e  = edge2[i];     // (src, eid), per-lane sequential 8B
            const float ev  = erow[e.y];  // gather within 36KB row (L1/L2)
            const float xsv = xs[e.x];    // LDS gather
            float v = fmaf(cL, xsv, fmaf(cE, ev, vb));
            v = (v >= 0.f) ? v : 0.2f * v;
            const float ex = __expf(v);
            den += ex;
            num = fmaf(ex, xsv, num);
        }
        if (end > beg) acc = num / den;
    }

    // block reduce (5 waves)
    for (int off = 32; off > 0; off >>= 1) acc += __shfl_down(acc, off);
    if ((tid & 63) == 0) red[tid >> 6] = acc;
    __syncthreads();
    if (tid == 0) S[g] = red[0] + red[1] + red[2] + red[3] + red[4];
}

// ---------------------------------------------------------------------------
// Kernel 3: GRU (24 steps, hidden 12) in wave 0 via shuffles (0 barriers in
// the time loop), then FC (12 -> 1200) across all 256 threads.
// pooled[b,t,o] = (S[g]/N) * w_node[o] + gat_bias[o]
// ---------------------------------------------------------------------------
__device__ __forceinline__ float sigmoidf_(float v) { return 1.0f / (1.0f + __expf(-v)); }

__global__ __launch_bounds__(256) void gru_fc(
    const float* __restrict__ S,
    const float* __restrict__ w_node, const float* __restrict__ gat_bias,
    const float* __restrict__ w_ih, const float* __restrict__ w_hh,
    const float* __restrict__ b_ih, const float* __restrict__ b_hh,
    const float* __restrict__ fc_w, const float* __restrict__ fc_b,
    float* __restrict__ out)
{
    __shared__ float hsh[GRUH];

    const int b = blockIdx.x;
    const int tid = threadIdx.x;

    if (tid < 64) {  // wave 0 runs the whole GRU, barrier-free
        float wn[4], gb[4];
#pragma unroll
        for (int i = 0; i < 4; i++) {
            wn[i] = w_node[i] * (1.0f / (float)NN);
            gb[i] = gat_bias[i];
        }
        float wih[4] = {0.f, 0.f, 0.f, 0.f};
        float whh[12];
#pragma unroll
        for (int j = 0; j < 12; j++) whh[j] = 0.f;
        float bih = 0.f, bhh = 0.f;
        if (tid < 36) {
#pragma unroll
            for (int i = 0; i < 4; i++)  wih[i] = w_ih[tid * 4 + i];
#pragma unroll
            for (int j = 0; j < 12; j++) whh[j] = w_hh[tid * 12 + j];
            bih = b_ih[tid];
            bhh = b_hh[tid];
        }
        // preload this batch's 24 pooled scalars across lanes 0..23
        float srow = (tid < T_) ? S[(size_t)b * T_ + tid] : 0.f;

        float hreg = 0.f;          // lanes 0..11 hold h
        const int l = tid % 12;    // safe shuffle index for every lane

        for (int t = 0; t < T_; t++) {
            float Sg = __shfl(srow, t);
            float gi = bih, gh = bhh;
#pragma unroll
            for (int i = 0; i < 4; i++) gi += (Sg * wn[i] + gb[i]) * wih[i];
#pragma unroll
            for (int j = 0; j < 12; j++) gh += __shfl(hreg, j) * whh[j];
            float a   = gi + gh;                 // lane m<36: gate-preact m
            float aiz = __shfl(a, 12 + l);       // z-gate preact for lane l
            float gin = __shfl(gi, 24 + l);      // n-gate input part
            float ghn = __shfl(gh, 24 + l);      // n-gate hidden part
            if (tid < 12) {
                float r = sigmoidf_(a);
                float z = sigmoidf_(aiz);
                float n = tanhf(gin + r * ghn);
                hreg = (1.f - z) * n + z * hreg;
            }
        }
        if (tid < GRUH) hsh[tid] = hreg;
    }
    __syncthreads();

    // FC epilogue: 1200 outputs per batch across 256 lanes (fc_w L1/L2-resident)
    for (int j = tid; j < OUTF; j += 256) {
        float o = fc_b[j];
#pragma unroll
        for (int k = 0; k < GRUH; k++) o += hsh[k] * fc_w[j * GRUH + k];
        out[(size_t)b * OUTF + j] = o;
    }
}

// ---------------------------------------------------------------------------
extern "C" void kernel_launch(void* const* d_in, const int* in_sizes, int n_in,
                              void* d_out, int out_size, void* d_ws, size_t ws_size,
                              hipStream_t stream)
{
    const float* x        = (const float*)d_in[0];
    const float* ew       = (const float*)d_in[1];
    const int*   src      = (const int*)d_in[2];
    const int*   dst      = (const int*)d_in[3];
    const float* w_node   = (const float*)d_in[4];
    const float* w_edge   = (const float*)d_in[5];
    const float* attn_l   = (const float*)d_in[6];
    const float* attn_r   = (const float*)d_in[7];
    const float* attn_e   = (const float*)d_in[8];
    const float* gat_bias = (const float*)d_in[9];
    const float* w_ih     = (const float*)d_in[10];
    const float* w_hh     = (const float*)d_in[11];
    const float* b_ih     = (const float*)d_in[12];
    const float* b_hh     = (const float*)d_in[13];
    const float* fc_w     = (const float*)d_in[14];
    const float* fc_b     = (const float*)d_in[15];
    float* out = (float*)d_out;

    // workspace layout: S[GG] f32 | row_ptr[304] i32 | edge2[EE] int2
    char* ws = (char*)d_ws;
    float* S       = (float*)ws;
    int*   row_ptr = (int*)(ws + GG * sizeof(float));
    int2*  edge2   = (int2*)(ws + GG * sizeof(float) + 304 * sizeof(int));

    build_csr<<<1, 1024, 0, stream>>>(src, dst, row_ptr, edge2);
    gat_pool<<<GG, 320, 0, stream>>>(x, ew, w_node, w_edge,
                                     attn_l, attn_r, attn_e,
                                     row_ptr, edge2, S);
    gru_fc<<<B_, 256, 0, stream>>>(S, w_node, gat_bias, w_ih, w_hh,
                                   b_ih, b_hh, fc_w, fc_b, out);
}

// Round 3
// 275.105 us; speedup vs baseline: 1.6915x; 1.6292x over previous
//
#include <hip/hip_runtime.h>
#include <math.h>

#define B_    128
#define T_    24
#define NN    300
#define EE    9000
#define GG    (B_ * T_)
#define GRUH  12
#define OUTF  1200

#define NSPLIT   50     // node splits (300 = 50 * 6)
#define NODES_PER 6
#define GCHUNKS  48     // 3072 / 64

// ---------------------------------------------------------------------------
// Kernel 0: tiled transpose  src[3072][ncols] -> dst[ncols][3072]
// 64x64 tiles via LDS, float4 both sides, coalesced 256B+ segments.
// ---------------------------------------------------------------------------
__global__ __launch_bounds__(256) void transpose_k(
    const float* __restrict__ src, float* __restrict__ dst, int ncols)
{
    __shared__ float tile[64][65];
    const int g0 = blockIdx.x * 64;          // row tile in src (graph dim, 3072 exact)
    const int e0 = blockIdx.y * 64;          // col tile in src
    const int tid = threadIdx.x;
    const int rr = tid >> 4;                 // 0..15
    const int c4 = (tid & 15) << 2;          // 0,4,...,60
    const int cols_here = min(64, ncols - e0);   // multiple of 4 for our shapes

#pragma unroll
    for (int k = 0; k < 4; k++) {
        const int r = rr + k * 16;
        if (c4 < cols_here) {
            const float4 v = *(const float4*)(src + (size_t)(g0 + r) * ncols + e0 + c4);
            tile[r][c4 + 0] = v.x; tile[r][c4 + 1] = v.y;
            tile[r][c4 + 2] = v.z; tile[r][c4 + 3] = v.w;
        }
    }
    __syncthreads();
#pragma unroll
    for (int k = 0; k < 4; k++) {
        const int er = rr + k * 16;
        if (er < cols_here) {
            float4 v;
            v.x = tile[c4 + 0][er]; v.y = tile[c4 + 1][er];
            v.z = tile[c4 + 2][er]; v.w = tile[c4 + 3][er];
            *(float4*)(dst + (size_t)(e0 + er) * GG + g0 + c4) = v;
        }
    }
}

// ---------------------------------------------------------------------------
// Kernel 1: build CSR of edges grouped by dst (shared topology), + zero S.
// ---------------------------------------------------------------------------
__global__ __launch_bounds__(1024) void build_csr(
    const int* __restrict__ src, const int* __restrict__ dst,
    int* __restrict__ row_ptr, int2* __restrict__ edge2, float* __restrict__ S)
{
    __shared__ int cnt[512];
    __shared__ int bufA[512], bufB[512];
    __shared__ int offs[NN];
    const int tid = threadIdx.x;

    for (int i = tid; i < GG; i += 1024) S[i] = 0.f;   // zero accumulators

    for (int i = tid; i < 512; i += 1024) cnt[i] = 0;
    __syncthreads();
    for (int e = tid; e < EE; e += 1024) atomicAdd(&cnt[dst[e]], 1);
    __syncthreads();

    int* cur = bufA; int* nxt = bufB;
    if (tid < 512) cur[tid] = cnt[tid];
    __syncthreads();
    for (int d = 1; d < 512; d <<= 1) {
        if (tid < 512) nxt[tid] = cur[tid] + (tid >= d ? cur[tid - d] : 0);
        __syncthreads();
        int* t = cur; cur = nxt; nxt = t;
    }
    if (tid <= NN) row_ptr[tid] = (tid == 0) ? 0 : cur[tid - 1];
    if (tid < NN)  offs[tid]    = (tid == 0) ? 0 : cur[tid - 1];
    __syncthreads();

    for (int e = tid; e < EE; e += 1024) {
        int d = dst[e];
        int pos = atomicAdd(&offs[d], 1);
        edge2[pos] = make_int2(src[e], e);
    }
}

// ---------------------------------------------------------------------------
// Kernel 2: EdgeGAT + mean pool, lane = graph. One wave per (64-graph chunk,
// 6-node split). Scalar (wave-uniform) indices, fully coalesced data loads,
// zero gathers, zero divergence, register accumulators.
// ---------------------------------------------------------------------------
__global__ __launch_bounds__(64) void gat_pool_t(
    const float* __restrict__ ewT, const float* __restrict__ xT,
    const float* __restrict__ w_node, const float* __restrict__ w_edge,
    const float* __restrict__ attn_l, const float* __restrict__ attn_r,
    const float* __restrict__ attn_e,
    const int* __restrict__ row_ptr, const int2* __restrict__ edge2,
    float* __restrict__ S)
{
    const int lane  = threadIdx.x;
    const int chunk = blockIdx.x % GCHUNKS;
    const int s     = blockIdx.x / GCHUNKS;
    const int g     = chunk * 64 + lane;

    float cL = 0.f, cR = 0.f, cE = 0.f;
#pragma unroll
    for (int o = 0; o < 4; o++) {
        float wn = w_node[o];
        cL += wn * attn_l[o];
        cR += wn * attn_r[o];
        cE += w_edge[o] * attn_e[o];
    }

    float part = 0.f;
    const int n0 = s * NODES_PER;
    for (int n = n0; n < n0 + NODES_PER; n++) {
        const int beg = row_ptr[n];
        const int end = row_ptr[n + 1];
        const float base = cR * xT[(size_t)n * GG + g];   // dst term (uniform row)
        float den = 0.f, num = 0.f;
        int i = beg;
        for (; i + 4 <= end; i += 4) {
            const int2 ea = edge2[i];
            const int2 eb = edge2[i + 1];
            const int2 ec = edge2[i + 2];
            const int2 ed = edge2[i + 3];
            const float wa = ewT[(size_t)ea.y * GG + g];
            const float wb = ewT[(size_t)eb.y * GG + g];
            const float wc = ewT[(size_t)ec.y * GG + g];
            const float wd = ewT[(size_t)ed.y * GG + g];
            const float xa = xT[(size_t)ea.x * GG + g];
            const float xb = xT[(size_t)eb.x * GG + g];
            const float xc = xT[(size_t)ec.x * GG + g];
            const float xd = xT[(size_t)ed.x * GG + g];
            float v0 = fmaf(cL, xa, fmaf(cE, wa, base));
            float v1 = fmaf(cL, xb, fmaf(cE, wb, base));
            float v2 = fmaf(cL, xc, fmaf(cE, wc, base));
            float v3 = fmaf(cL, xd, fmaf(cE, wd, base));
            v0 = (v0 >= 0.f) ? v0 : 0.2f * v0;
            v1 = (v1 >= 0.f) ? v1 : 0.2f * v1;
            v2 = (v2 >= 0.f) ? v2 : 0.2f * v2;
            v3 = (v3 >= 0.f) ? v3 : 0.2f * v3;
            const float e0 = __expf(v0), e1 = __expf(v1);
            const float e2 = __expf(v2), e3 = __expf(v3);
            den += e0 + e1 + e2 + e3;
            num = fmaf(e0, xa, num);
            num = fmaf(e1, xb, num);
            num = fmaf(e2, xc, num);
            num = fmaf(e3, xd, num);
        }
        for (; i < end; i++) {
            const int2 ea = edge2[i];
            const float wa = ewT[(size_t)ea.y * GG + g];
            const float xa = xT[(size_t)ea.x * GG + g];
            float v0 = fmaf(cL, xa, fmaf(cE, wa, base));
            v0 = (v0 >= 0.f) ? v0 : 0.2f * v0;
            const float e0 = __expf(v0);
            den += e0;
            num = fmaf(e0, xa, num);
        }
        if (end > beg) part += num / den;
    }
    unsafeAtomicAdd(&S[g], part);
}

// ---------------------------------------------------------------------------
// Kernel 3: GRU (24 steps, hidden 12) — one wave per batch, shuffle-only.
// pooled[b,t,o] = (S[g]/N) * w_node[o] + gat_bias[o].  Writes hT[b][12].
// ---------------------------------------------------------------------------
__device__ __forceinline__ float sigmoidf_(float v) { return 1.0f / (1.0f + __expf(-v)); }

__global__ __launch_bounds__(64) void gru_k(
    const float* __restrict__ S,
    const float* __restrict__ w_node, const float* __restrict__ gat_bias,
    const float* __restrict__ w_ih, const float* __restrict__ w_hh,
    const float* __restrict__ b_ih, const float* __restrict__ b_hh,
    float* __restrict__ hT)
{
    const int b = blockIdx.x;
    const int tid = threadIdx.x;

    float wn[4], gb[4];
#pragma unroll
    for (int i = 0; i < 4; i++) {
        wn[i] = w_node[i] * (1.0f / (float)NN);
        gb[i] = gat_bias[i];
    }
    float wih[4] = {0.f, 0.f, 0.f, 0.f};
    float whh[12];
#pragma unroll
    for (int j = 0; j < 12; j++) whh[j] = 0.f;
    float bih = 0.f, bhh = 0.f;
    if (tid < 36) {
#pragma unroll
        for (int i = 0; i < 4; i++)  wih[i] = w_ih[tid * 4 + i];
#pragma unroll
        for (int j = 0; j < 12; j++) whh[j] = w_hh[tid * 12 + j];
        bih = b_ih[tid];
        bhh = b_hh[tid];
    }
    float srow = (tid < T_) ? S[(size_t)b * T_ + tid] : 0.f;

    float hreg = 0.f;
    const int l = tid % 12;

    for (int t = 0; t < T_; t++) {
        float Sg = __shfl(srow, t);
        float gi = bih, gh = bhh;
#pragma unroll
        for (int i = 0; i < 4; i++) gi += (Sg * wn[i] + gb[i]) * wih[i];
#pragma unroll
        for (int j = 0; j < 12; j++) gh += __shfl(hreg, j) * whh[j];
        float a   = gi + gh;
        float aiz = __shfl(a, 12 + l);
        float gin = __shfl(gi, 24 + l);
        float ghn = __shfl(gh, 24 + l);
        if (tid < 12) {
            float r = sigmoidf_(a);
            float z = sigmoidf_(aiz);
            float n = tanhf(gin + r * ghn);
            hreg = (1.f - z) * n + z * hreg;
        }
    }
    if (tid < GRUH) hT[(size_t)b * GRUH + tid] = hreg;
}

// ---------------------------------------------------------------------------
// Kernel 4: FC 12 -> 1200, one output per thread, float4 weight rows.
// grid (128, 5), block 256 (240 active).
// ---------------------------------------------------------------------------
__global__ __launch_bounds__(256) void fc_k(
    const float* __restrict__ hT, const float* __restrict__ fc_w,
    const float* __restrict__ fc_b, float* __restrict__ out)
{
    __shared__ float h[GRUH];
    const int b = blockIdx.x;
    const int tid = threadIdx.x;
    if (tid < GRUH) h[tid] = hT[(size_t)b * GRUH + tid];
    __syncthreads();
    const int j = blockIdx.y * 240 + tid;
    if (tid < 240) {
        const float4* w4 = (const float4*)(fc_w + (size_t)j * GRUH);
        const float4 a = w4[0], c = w4[1], d = w4[2];
        float o = fc_b[j];
        o += h[0] * a.x + h[1] * a.y + h[2]  * a.z + h[3]  * a.w;
        o += h[4] * c.x + h[5] * c.y + h[6]  * c.z + h[7]  * c.w;
        o += h[8] * d.x + h[9] * d.y + h[10] * d.z + h[11] * d.w;
        out[(size_t)b * OUTF + j] = o;
    }
}

// ---------------------------------------------------------------------------
// Fallback path (small workspace): round-2 kernels
// ---------------------------------------------------------------------------
__global__ __launch_bounds__(320) void gat_pool_csr(
    const float* __restrict__ x, const float* __restrict__ ew,
    const float* __restrict__ w_node, const float* __restrict__ w_edge,
    const float* __restrict__ attn_l, const float* __restrict__ attn_r,
    const float* __restrict__ attn_e,
    const int* __restrict__ row_ptr, const int2* __restrict__ edge2,
    float* __restrict__ S)
{
    __shared__ float xs[NN];
    __shared__ float red[5];
    const int g = blockIdx.x;
    const int tid = threadIdx.x;

    float cL = 0.f, cR = 0.f, cE = 0.f;
#pragma unroll
    for (int o = 0; o < 4; o++) {
        float wn = w_node[o];
        cL += wn * attn_l[o];
        cR += wn * attn_r[o];
        cE += w_edge[o] * attn_e[o];
    }
    const float* xrow = x + (size_t)g * NN;
    const float* erow = ew + (size_t)g * EE;
    for (int i = tid; i < NN; i += 320) xs[i] = xrow[i];
    __syncthreads();

    float acc = 0.f;
    if (tid < NN) {
        const int beg = row_ptr[tid];
        const int end = row_ptr[tid + 1];
        const float vb = cR * xs[tid];
        float den = 0.f, num = 0.f;
        for (int i = beg; i < end; i++) {
            const int2 e  = edge2[i];
            const float ev  = erow[e.y];
            const float xsv = xs[e.x];
            float v = fmaf(cL, xsv, fmaf(cE, ev, vb));
            v = (v >= 0.f) ? v : 0.2f * v;
            const float ex = __expf(v);
            den += ex;
            num = fmaf(ex, xsv, num);
        }
        if (end > beg) acc = num / den;
    }
    for (int off = 32; off > 0; off >>= 1) acc += __shfl_down(acc, off);
    if ((tid & 63) == 0) red[tid >> 6] = acc;
    __syncthreads();
    if (tid == 0) S[g] = red[0] + red[1] + red[2] + red[3] + red[4];
}

__global__ __launch_bounds__(256) void gru_fc_fused(
    const float* __restrict__ S,
    const float* __restrict__ w_node, const float* __restrict__ gat_bias,
    const float* __restrict__ w_ih, const float* __restrict__ w_hh,
    const float* __restrict__ b_ih, const float* __restrict__ b_hh,
    const float* __restrict__ fc_w, const float* __restrict__ fc_b,
    float* __restrict__ out)
{
    __shared__ float hsh[GRUH];
    const int b = blockIdx.x;
    const int tid = threadIdx.x;

    if (tid < 64) {
        float wn[4], gb[4];
#pragma unroll
        for (int i = 0; i < 4; i++) {
            wn[i] = w_node[i] * (1.0f / (float)NN);
            gb[i] = gat_bias[i];
        }
        float wih[4] = {0.f, 0.f, 0.f, 0.f};
        float whh[12];
#pragma unroll
        for (int j = 0; j < 12; j++) whh[j] = 0.f;
        float bih = 0.f, bhh = 0.f;
        if (tid < 36) {
#pragma unroll
            for (int i = 0; i < 4; i++)  wih[i] = w_ih[tid * 4 + i];
#pragma unroll
            for (int j = 0; j < 12; j++) whh[j] = w_hh[tid * 12 + j];
            bih = b_ih[tid];
            bhh = b_hh[tid];
        }
        float srow = (tid < T_) ? S[(size_t)b * T_ + tid] : 0.f;
        float hreg = 0.f;
        const int l = tid % 12;
        for (int t = 0; t < T_; t++) {
            float Sg = __shfl(srow, t);
            float gi = bih, gh = bhh;
#pragma unroll
            for (int i = 0; i < 4; i++) gi += (Sg * wn[i] + gb[i]) * wih[i];
#pragma unroll
            for (int j = 0; j < 12; j++) gh += __shfl(hreg, j) * whh[j];
            float a   = gi + gh;
            float aiz = __shfl(a, 12 + l);
            float gin = __shfl(gi, 24 + l);
            float ghn = __shfl(gh, 24 + l);
            if (tid < 12) {
                float r = sigmoidf_(a);
                float z = sigmoidf_(aiz);
                float n = tanhf(gin + r * ghn);
                hreg = (1.f - z) * n + z * hreg;
            }
        }
        if (tid < GRUH) hsh[tid] = hreg;
    }
    __syncthreads();
    for (int j = tid; j < OUTF; j += 256) {
        float o = fc_b[j];
#pragma unroll
        for (int k = 0; k < GRUH; k++) o += hsh[k] * fc_w[j * GRUH + k];
        out[(size_t)b * OUTF + j] = o;
    }
}

// ---------------------------------------------------------------------------
extern "C" void kernel_launch(void* const* d_in, const int* in_sizes, int n_in,
                              void* d_out, int out_size, void* d_ws, size_t ws_size,
                              hipStream_t stream)
{
    const float* x        = (const float*)d_in[0];
    const float* ew       = (const float*)d_in[1];
    const int*   src      = (const int*)d_in[2];
    const int*   dst      = (const int*)d_in[3];
    const float* w_node   = (const float*)d_in[4];
    const float* w_edge   = (const float*)d_in[5];
    const float* attn_l   = (const float*)d_in[6];
    const float* attn_r   = (const float*)d_in[7];
    const float* attn_e   = (const float*)d_in[8];
    const float* gat_bias = (const float*)d_in[9];
    const float* w_ih     = (const float*)d_in[10];
    const float* w_hh     = (const float*)d_in[11];
    const float* b_ih     = (const float*)d_in[12];
    const float* b_hh     = (const float*)d_in[13];
    const float* fc_w     = (const float*)d_in[14];
    const float* fc_b     = (const float*)d_in[15];
    float* out = (float*)d_out;

    char* ws = (char*)d_ws;
    const size_t ewT_b  = (size_t)EE * GG * 4;            // 110,592,000
    const size_t xT_b   = (size_t)NN * GG * 4;            //   3,686,400
    const size_t needed = ewT_b + xT_b + GG * 4 + 1280 + (size_t)EE * 8 + B_ * GRUH * 4;

    if (ws_size >= needed) {
        float* ewT     = (float*)ws;
        float* xT      = (float*)(ws + ewT_b);
        float* S       = (float*)(ws + ewT_b + xT_b);
        int*   row_ptr = (int*)(ws + ewT_b + xT_b + GG * 4);
        int2*  edge2   = (int2*)(ws + ewT_b + xT_b + GG * 4 + 1280);
        float* hT      = (float*)(ws + ewT_b + xT_b + GG * 4 + 1280 + (size_t)EE * 8);

        transpose_k<<<dim3(GCHUNKS, (EE + 63) / 64), 256, 0, stream>>>(ew, ewT, EE);
        transpose_k<<<dim3(GCHUNKS, (NN + 63) / 64), 256, 0, stream>>>(x, xT, NN);
        build_csr<<<1, 1024, 0, stream>>>(src, dst, row_ptr, edge2, S);
        gat_pool_t<<<GCHUNKS * NSPLIT, 64, 0, stream>>>(ewT, xT, w_node, w_edge,
                                                        attn_l, attn_r, attn_e,
                                                        row_ptr, edge2, S);
        gru_k<<<B_, 64, 0, stream>>>(S, w_node, gat_bias, w_ih, w_hh, b_ih, b_hh, hT);
        fc_k<<<dim3(B_, 5), 256, 0, stream>>>(hT, fc_w, fc_b, out);
    } else {
        // small-workspace fallback (round-2 structure)
        float* S       = (float*)ws;
        int*   row_ptr = (int*)(ws + GG * 4);
        int2*  edge2   = (int2*)(ws + GG * 4 + 1280);
        build_csr<<<1, 1024, 0, stream>>>(src, dst, row_ptr, edge2, S);
        gat_pool_csr<<<GG, 320, 0, stream>>>(x, ew, w_node, w_edge,
                                             attn_l, attn_r, attn_e,
                                             row_ptr, edge2, S);
        gru_fc_fused<<<B_, 256, 0, stream>>>(S, w_node, gat_bias, w_ih, w_hh,
                                             b_ih, b_hh, fc_w, fc_b, out);
    }
}